// Round 1
// baseline (150.695 us; speedup 1.0000x reference)
//
#include <hip/hip_runtime.h>

// EuclideanLoss: loss = mean_n [ w_n * mean_b sqrt(sum_d (x[b,n,d]-y[b,d,n])^2) ]
// w_n = 1.5 for n in {1,2}, else 1.0. B=32, N=8192, D=64, fp32.
// Memory-bound: 128 MiB read -> ~20 us floor at 6.3 TB/s.

constexpr int B = 32;
constexpr int N = 8192;
constexpr int D = 64;

__global__ __launch_bounds__(256) void euclid_loss_kernel(
    const float* __restrict__ x,   // [B, N, D]
    const float* __restrict__ y,   // [B, D, N]
    float* __restrict__ out)       // [1]
{
    const int tid = threadIdx.x;
    const int n   = blockIdx.x * 256 + tid;
    const int b   = blockIdx.y;

    const float* xrow = x + ((size_t)b * N + n) * D;   // contiguous in d
    const float* ycol = y + (size_t)b * D * N + n;     // stride N in d, lane-coalesced

    float acc = 0.0f;
#pragma unroll
    for (int d = 0; d < D; d += 4) {
        const float4 xv = *reinterpret_cast<const float4*>(xrow + d);
        const float y0 = ycol[(size_t)(d + 0) * N];
        const float y1 = ycol[(size_t)(d + 1) * N];
        const float y2 = ycol[(size_t)(d + 2) * N];
        const float y3 = ycol[(size_t)(d + 3) * N];
        const float d0 = xv.x - y0;
        const float d1 = xv.y - y1;
        const float d2 = xv.z - y2;
        const float d3 = xv.w - y3;
        acc += d0 * d0 + d1 * d1 + d2 * d2 + d3 * d3;
    }

    const float w = (n == 1 || n == 2) ? 1.5f : 1.0f;
    float v = w * sqrtf(acc);

    // wave (64-lane) shuffle reduction
#pragma unroll
    for (int off = 32; off > 0; off >>= 1) v += __shfl_down(v, off, 64);

    __shared__ float wsum[4];
    if ((tid & 63) == 0) wsum[tid >> 6] = v;
    __syncthreads();

    if (tid == 0) {
        const float s = (wsum[0] + wsum[1] + wsum[2] + wsum[3]) *
                        (1.0f / (float)(B * N));
        atomicAdd(out, s);
    }
}

extern "C" void kernel_launch(void* const* d_in, const int* in_sizes, int n_in,
                              void* d_out, int out_size, void* d_ws, size_t ws_size,
                              hipStream_t stream) {
    const float* x = (const float*)d_in[0];
    const float* y = (const float*)d_in[1];
    float* out = (float*)d_out;

    // d_out is re-poisoned to 0xAA before every timed launch; zero it first
    // (async memset is graph-capturable).
    hipMemsetAsync(out, 0, sizeof(float), stream);

    dim3 grid(N / 256, B);
    euclid_loss_kernel<<<grid, 256, 0, stream>>>(x, y, out);
}